// Round 4
// baseline (845.233 us; speedup 1.0000x reference)
//
#include <hip/hip_runtime.h>
#include <hip/hip_bf16.h>
#include <stdint.h>

// Problem constants
#define T_TREES 16
#define B_ROWS  8192
#define DIN     512
#define DH      1024
#define DOUT    256

typedef unsigned short u16;
typedef __attribute__((ext_vector_type(8))) short short8;
typedef __attribute__((ext_vector_type(16))) float floatx16;

// round-to-nearest-even fp32 -> bf16
__device__ __forceinline__ u16 f2bf(float f) {
    union { float f; uint32_t u; } v; v.f = f;
    uint32_t u = v.u;
    uint32_t r = (u + 0x7fffu + ((u >> 16) & 1u)) >> 16;
    return (u16)r;
}

// async 16B/lane global->LDS (lands at wave-uniform base + lane*16)
__device__ __forceinline__ void async_copy16(const u16* g, u16* l) {
    __builtin_amdgcn_global_load_lds(
        (const __attribute__((address_space(1))) uint32_t*)g,
        (__attribute__((address_space(3))) uint32_t*)l,
        16, 0, 0);
}

// ---------------------------------------------------------------------------
// Fused prep, single launch:
//   blocks [0,4096):      convert x fp32->bf16
//   blocks [4096,12288):  out = mean_t b3
//   blocks [12288,40960): convert+transpose all weights (N x K layout)
__global__ void prep_kernel(const float* __restrict__ x, u16* __restrict__ xb,
                            const float* __restrict__ b3, float* __restrict__ out,
                            const float* __restrict__ W1, const float* __restrict__ W2,
                            const float* __restrict__ W3,
                            u16* __restrict__ W1b, u16* __restrict__ W2b,
                            u16* __restrict__ W3b) {
    __shared__ float tile[32][33];
    if (blockIdx.x < 4096) {
        int idx = blockIdx.x * 256 + threadIdx.x;
        float4 v = ((const float4*)x)[idx];
        ushort4 o;
        o.x = f2bf(v.x); o.y = f2bf(v.y); o.z = f2bf(v.z); o.w = f2bf(v.w);
        ((ushort4*)xb)[idx] = o;
    } else if (blockIdx.x < 12288) {
        int idx = (blockIdx.x - 4096) * 256 + threadIdx.x;
        int o = idx & (DOUT - 1);
        float s = 0.f;
#pragma unroll
        for (int t = 0; t < T_TREES; t++) s += b3[t * DOUT + o];
        out[idx] = s * (1.f / T_TREES);
    } else {
        int bid = blockIdx.x - 12288;
        int t = bid / 1792, tl = bid - t * 1792;
        const float* in; u16* outp; int K, N, kt, nt; float scale = 1.f;
        if (tl < 512)       { in = W1; outp = W1b; K = DIN; N = DH;   kt = tl & 15; nt = tl >> 4; }
        else if (tl < 1536) { tl -= 512;  in = W2; outp = W2b; K = DH; N = DH;   kt = tl & 31; nt = tl >> 5; }
        else                { tl -= 1536; in = W3; outp = W3b; K = DH; N = DOUT; kt = tl & 31; nt = tl >> 5;
                              scale = 1.f / T_TREES; }
        int k0 = kt * 32, n0 = nt * 32;
        const float* inb = in + (size_t)t * K * N;
        u16* outb = outp + (size_t)t * K * N;
        // float4-vectorized tile load: 32 rows x 8 float4
        int c4 = threadIdx.x & 7, rr = threadIdx.x >> 3;
        float4 v = *(const float4*)&inb[(size_t)(k0 + rr) * N + n0 + c4 * 4];
        tile[rr][c4 * 4 + 0] = v.x;
        tile[rr][c4 * 4 + 1] = v.y;
        tile[rr][c4 * 4 + 2] = v.z;
        tile[rr][c4 * 4 + 3] = v.w;
        __syncthreads();
        // vectorized transposed store: threads 0..127 write one 16B segment
        // (8 contiguous u16 of an output row). LDS column reads are 2-way
        // bank-aliased (free, m136).
        if (threadIdx.x < 128) {
            int n  = threadIdx.x >> 2;   // 0..31 output row (tile column)
            int kq = threadIdx.x & 3;    // 8-element quad along K
            short8 o;
#pragma unroll
            for (int j = 0; j < 8; j++)
                ((u16*)&o)[j] = f2bf(tile[kq * 8 + j][n] * scale);
            *(short8*)&outb[(size_t)(n0 + n) * K + k0 + kq * 8] = o;
        }
    }
}

// out[idx] += sum_{t<g} Part[t][idx]   (float4 vectorized)
__global__ void reduce_kernel(const float* __restrict__ Part, float* __restrict__ Out, int g) {
    int idx = blockIdx.x * 256 + threadIdx.x;  // over 524288 float4
    float4 s = ((const float4*)Out)[idx];
    for (int t = 0; t < g; t++) {
        float4 p = ((const float4*)(Part + (size_t)t * B_ROWS * DOUT))[idx];
        s.x += p.x; s.y += p.y; s.z += p.z; s.w += p.w;
    }
    ((float4*)Out)[idx] = s;
}

// ---------------------------------------------------------------------------
// Shared pieces: swizzle = logical 16B-slot q of row r lives at physical slot
// q ^ (r&7); staging stays LDS-linear and permutes the per-lane GLOBAL col
// (colE). A/B frag read: lane [row=base+l31][k-slot ((kk*2+h)^(l31&7))].
// C/D: col=lane&31, row=(reg&3)+8*(reg>>2)+4*(lane>>5)  [m74/m101].
// Pipeline (T3/T4): 2 tiles prefetched; per tile: vmcnt(8)+barrier, COMPUTE
// (setprio around MFMA clusters), barrier, STAGE(kt+2) into drained buffer.
// vmcnt never drains to 0 inside the loop.

#define GEMM_PREAMBLE_COMMON()                               \
    const int tid  = threadIdx.x;                            \
    const int wave = tid >> 6;                               \
    const int lane = tid & 63;                               \
    const int l31  = lane & 31;                              \
    const int h    = lane >> 5;                              \
    const int rg   = tid >> 3;                               \
    const int colE = (((tid & 7) ^ (rg & 7)) << 3);          \
    const int xm   = l31 & 7;

// ======================= 256x256 tile, 8 waves =============================
#define STAGE256(kt_, p_)                                                              \
    {                                                                                  \
        const int k0_ = (kt_) * 64;                                                    \
        u16* lA_ = lds + (p_) * 32768 + wave * 512;                                    \
        u16* lB_ = lA_ + 16384;                                                        \
        _Pragma("unroll")                                                              \
        for (int j_ = 0; j_ < 4; j_++) {                                               \
            const int row_ = j_ * 64 + rg;                                             \
            async_copy16(Ab + (size_t)(m0 + row_) * K + k0_ + colE, lA_ + j_ * 4096);  \
            async_copy16(Bb + (size_t)(n0 + row_) * K + k0_ + colE, lB_ + j_ * 4096);  \
        }                                                                              \
    }

#define COMPUTE256(p_)                                                                 \
    {                                                                                  \
        const u16* A_ = lds + (p_) * 32768;                                            \
        const u16* B_ = A_ + 16384;                                                    \
        short8 bfr[2][4];                                                              \
        _Pragma("unroll")                                                              \
        for (int nf = 0; nf < 2; nf++) {                                               \
            const int r_ = wn4 * 64 + nf * 32 + l31;                                   \
            _Pragma("unroll")                                                          \
            for (int kk = 0; kk < 4; kk++)                                             \
                bfr[nf][kk] = *(const short8*)&B_[r_ * 64 + (((kk * 2 + h) ^ xm) << 3)]; \
        }                                                                              \
        _Pragma("unroll")                                                              \
        for (int mh = 0; mh < 2; mh++) {                                               \
            short8 afr[2][4];                                                          \
            _Pragma("unroll")                                                          \
            for (int mf = 0; mf < 2; mf++) {                                           \
                const int r_ = wm2 * 128 + mh * 64 + mf * 32 + l31;                    \
                _Pragma("unroll")                                                      \
                for (int kk = 0; kk < 4; kk++)                                         \
                    afr[mf][kk] = *(const short8*)&A_[r_ * 64 + (((kk * 2 + h) ^ xm) << 3)]; \
            }                                                                          \
            __builtin_amdgcn_s_setprio(1);                                             \
            _Pragma("unroll")                                                          \
            for (int kk = 0; kk < 4; kk++)                                             \
                _Pragma("unroll")                                                      \
                for (int mf = 0; mf < 2; mf++)                                         \
                    _Pragma("unroll")                                                  \
                    for (int nf = 0; nf < 2; nf++)                                     \
                        acc[mh * 2 + mf][nf] = __builtin_amdgcn_mfma_f32_32x32x16_bf16(\
                            afr[mf][kk], bfr[nf][kk], acc[mh * 2 + mf][nf], 0, 0, 0);  \
            __builtin_amdgcn_s_setprio(0);                                             \
        }                                                                              \
    }

#define GEMM_MAIN(STAGE_, COMPUTE_)                                              \
    STAGE_(0, 0);                                                                \
    STAGE_(1, 1);                                                                \
    for (int kt = 0; kt < NT; kt++) {                                            \
        const int p_ = kt & 1;                                                   \
        if (kt < NT - 1) asm volatile("s_waitcnt vmcnt(8)\n\ts_barrier" ::: "memory"); \
        else             asm volatile("s_waitcnt vmcnt(0)\n\ts_barrier" ::: "memory"); \
        COMPUTE_(p_);                                                            \
        asm volatile("s_barrier" ::: "memory");                                  \
        if (kt + 2 < NT) STAGE_(kt + 2, p_);                                     \
    }

// L2: C[t] = relu(A[t] @ B[t]^T + bias[t]), 256x256 tile, 512 thr, 128KB LDS.
__global__ __launch_bounds__(512, 2)
void gemm_l2_256(const u16* __restrict__ A, size_t aStrideT,
                 const u16* __restrict__ Bt,
                 const float* __restrict__ bias,
                 u16* __restrict__ C,
                 int M, int N, int K) {
    extern __shared__ u16 lds[];

    const int t = blockIdx.z;
    const u16* Ab = A + (size_t)t * aStrideT;
    const u16* Bb = Bt + (size_t)t * (size_t)N * K;
    u16* Cb = C + (size_t)t * (size_t)M * N;
    const float* biasb = bias + (size_t)t * N;

    const int m0 = blockIdx.x * 256;
    const int n0 = blockIdx.y * 256;

    GEMM_PREAMBLE_COMMON();
    const int wm2 = wave >> 2;   // 0..1
    const int wn4 = wave & 3;    // 0..3

    floatx16 acc[4][2];
#pragma unroll
    for (int ai = 0; ai < 4; ai++)
#pragma unroll
        for (int nf = 0; nf < 2; nf++)
#pragma unroll
            for (int r = 0; r < 16; r++) acc[ai][nf][r] = 0.f;

    const int NT = K >> 6;
    GEMM_MAIN(STAGE256, COMPUTE256);

#pragma unroll
    for (int nf = 0; nf < 2; nf++) {
        const int n = n0 + wn4 * 64 + nf * 32 + l31;
        const float bv = biasb[n];
#pragma unroll
        for (int ai = 0; ai < 4; ai++) {
#pragma unroll
            for (int r = 0; r < 16; r++) {
                const int m = m0 + wm2 * 128 + ai * 32 + (r & 3) + 8 * (r >> 2) + 4 * h;
                float v = acc[ai][nf][r] + bv;
                v = v > 0.f ? v : 0.f;
                Cb[(size_t)m * N + n] = f2bf(v);
            }
        }
    }
}

// L3: Part[t] = H2[t] @ W3t[t]^T (fp32, no bias/relu; W3t pre-scaled 1/16).
// 256x256 tile: grid (32, 1, g) = 256 blocks at g=8 -> exactly one full
// 1-block/CU round, NT=16 deep pipeline.
__global__ __launch_bounds__(512, 2)
void gemm_l3_256(const u16* __restrict__ H2, const u16* __restrict__ W3t,
                 float* __restrict__ Part) {
    constexpr int M = B_ROWS, N = DOUT, K = DH;
    extern __shared__ u16 lds[];

    const int t = blockIdx.z;
    const u16* Ab = H2 + (size_t)t * M * K;
    const u16* Bb = W3t + (size_t)t * (size_t)N * K;
    float* Pb = Part + (size_t)t * (size_t)M * N;

    const int m0 = blockIdx.x * 256;
    const int n0 = 0;   // N == 256, single column block

    GEMM_PREAMBLE_COMMON();
    const int wm2 = wave >> 2;
    const int wn4 = wave & 3;

    floatx16 acc[4][2];
#pragma unroll
    for (int ai = 0; ai < 4; ai++)
#pragma unroll
        for (int nf = 0; nf < 2; nf++)
#pragma unroll
            for (int r = 0; r < 16; r++) acc[ai][nf][r] = 0.f;

    const int NT = K >> 6;
    GEMM_MAIN(STAGE256, COMPUTE256);

#pragma unroll
    for (int nf = 0; nf < 2; nf++) {
        const int n = n0 + wn4 * 64 + nf * 32 + l31;
#pragma unroll
        for (int ai = 0; ai < 4; ai++) {
#pragma unroll
            for (int r = 0; r < 16; r++) {
                const int m = m0 + wm2 * 128 + ai * 32 + (r & 3) + 8 * (r >> 2) + 4 * h;
                Pb[(size_t)m * N + n] = acc[ai][nf][r];
            }
        }
    }
}

// ======================= 128x128 tile, 4 waves (L1) ========================
#define STAGE128(kt_, p_)                                                              \
    {                                                                                  \
        const int k0_ = (kt_) * 64;                                                    \
        u16* lA_ = lds + (p_) * 16384 + wave * 512;                                    \
        u16* lB_ = lA_ + 8192;                                                         \
        _Pragma("unroll")                                                              \
        for (int j_ = 0; j_ < 4; j_++) {                                               \
            const int row_ = j_ * 32 + rg;                                             \
            async_copy16(Ab + (size_t)(m0 + row_) * K + k0_ + colE, lA_ + j_ * 2048);  \
            async_copy16(Bb + (size_t)(n0 + row_) * K + k0_ + colE, lB_ + j_ * 2048);  \
        }                                                                              \
    }

#define COMPUTE128(p_)                                                                 \
    {                                                                                  \
        const u16* A_ = lds + (p_) * 16384;                                            \
        const u16* B_ = A_ + 8192;                                                     \
        short8 bfr[2][4], afr[2][4];                                                   \
        _Pragma("unroll")                                                              \
        for (int nf = 0; nf < 2; nf++) {                                               \
            const int r_ = wn + nf * 32 + l31;                                         \
            _Pragma("unroll")                                                          \
            for (int kk = 0; kk < 4; kk++)                                             \
                bfr[nf][kk] = *(const short8*)&B_[r_ * 64 + (((kk * 2 + h) ^ xm) << 3)]; \
        }                                                                              \
        _Pragma("unroll")                                                              \
        for (int mf = 0; mf < 2; mf++) {                                               \
            const int r_ = wm + mf * 32 + l31;                                         \
            _Pragma("unroll")                                                          \
            for (int kk = 0; kk < 4; kk++)                                             \
                afr[mf][kk] = *(const short8*)&A_[r_ * 64 + (((kk * 2 + h) ^ xm) << 3)]; \
        }                                                                              \
        __builtin_amdgcn_s_setprio(1);                                                 \
        _Pragma("unroll")                                                              \
        for (int kk = 0; kk < 4; kk++)                                                 \
            _Pragma("unroll")                                                          \
            for (int mf = 0; mf < 2; mf++)                                             \
                _Pragma("unroll")                                                      \
                for (int nf = 0; nf < 2; nf++)                                         \
                    acc[mf][nf] = __builtin_amdgcn_mfma_f32_32x32x16_bf16(             \
                        afr[mf][kk], bfr[nf][kk], acc[mf][nf], 0, 0, 0);               \
        __builtin_amdgcn_s_setprio(0);                                                 \
    }

// L1: C[t] = relu(A @ B[t]^T + bias[t]), 128x128 tile, 256 thr, 64KB LDS.
__global__ __launch_bounds__(256, 2)
void gemm_l1_128(const u16* __restrict__ A, size_t aStrideT,
                 const u16* __restrict__ Bt,
                 const float* __restrict__ bias,
                 u16* __restrict__ C,
                 int M, int N, int K) {
    extern __shared__ u16 lds[];

    const int t = blockIdx.z;
    const u16* Ab = A + (size_t)t * aStrideT;
    const u16* Bb = Bt + (size_t)t * (size_t)N * K;
    u16* Cb = C + (size_t)t * (size_t)M * N;
    const float* biasb = bias + (size_t)t * N;

    const int m0 = blockIdx.x * 128;
    const int n0 = blockIdx.y * 128;

    GEMM_PREAMBLE_COMMON();
    const int wm = (wave >> 1) * 64;
    const int wn = (wave & 1) * 64;

    floatx16 acc[2][2];
#pragma unroll
    for (int mf = 0; mf < 2; mf++)
#pragma unroll
        for (int nf = 0; nf < 2; nf++)
#pragma unroll
            for (int r = 0; r < 16; r++) acc[mf][nf][r] = 0.f;

    const int NT = K >> 6;
    GEMM_MAIN(STAGE128, COMPUTE128);

#pragma unroll
    for (int nf = 0; nf < 2; nf++) {
        const int n = n0 + wn + nf * 32 + l31;
        const float bv = biasb[n];
#pragma unroll
        for (int mf = 0; mf < 2; mf++) {
#pragma unroll
            for (int r = 0; r < 16; r++) {
                const int m = m0 + wm + mf * 32 + (r & 3) + 8 * (r >> 2) + 4 * h;
                float v = acc[mf][nf][r] + bv;
                v = v > 0.f ? v : 0.f;
                Cb[(size_t)m * N + n] = f2bf(v);
            }
        }
    }
}

// ---------------------------------------------------------------------------
extern "C" void kernel_launch(void* const* d_in, const int* in_sizes, int n_in,
                              void* d_out, int out_size, void* d_ws, size_t ws_size,
                              hipStream_t stream) {
    const float* x  = (const float*)d_in[0];
    const float* W1 = (const float*)d_in[1];
    const float* b1 = (const float*)d_in[2];
    const float* W2 = (const float*)d_in[3];
    const float* b2 = (const float*)d_in[4];
    const float* W3 = (const float*)d_in[5];
    const float* b3 = (const float*)d_in[6];
    float* out = (float*)d_out;

    // workspace: fixed 64 MB (xb 8 + W1b 16 + W2b 32 + W3b 8), then h1/h2.
    // Partial planes (g x 8 MB fp32) reuse the h1 region (free after L2).
    const size_t XB_BYTES = 8388608ull;
    const size_t W1B_BYTES = 16777216ull, W2B_BYTES = 33554432ull, W3B_BYTES = 8388608ull;
    const size_t FIXED = XB_BYTES + W1B_BYTES + W2B_BYTES + W3B_BYTES;  // 67,108,864
    const size_t PER_TREE = 33554432ull;  // h1 16 MB + h2 16 MB

    uint8_t* ws = (uint8_t*)d_ws;
    u16* xb  = (u16*)ws;
    u16* W1b = (u16*)(ws + XB_BYTES);
    u16* W2b = (u16*)(ws + XB_BYTES + W1B_BYTES);
    u16* W3b = (u16*)(ws + XB_BYTES + W1B_BYTES + W2B_BYTES);
    u16* h1  = (u16*)(ws + FIXED);
    float* part = (float*)(ws + FIXED);   // aliases h1 (safe: h1 dead after L2)

    int g = 16;
    while (g > 1 && FIXED + (size_t)g * PER_TREE > ws_size) g >>= 1;
    const int nG = T_TREES / g;
    u16* h2 = (u16*)(ws + FIXED + (size_t)g * (PER_TREE / 2));

    prep_kernel<<<12288 + 1792 * T_TREES, 256, 0, stream>>>(
        x, xb, b3, out, W1, W2, W3, W1b, W2b, W3b);

    const uint32_t LDS256 = 131072;  // 2 dbuf x (A+B) x 32 KB
    const uint32_t LDS128 = 65536;   // 2 dbuf x (A+B) x 16 KB

    for (int gi = 0; gi < nG; gi++) {
        const int t0 = gi * g;
        gemm_l1_128<<<dim3(B_ROWS / 128, DH / 128, g), 256, LDS128, stream>>>(
            xb, 0, W1b + (size_t)t0 * DIN * DH, b1 + (size_t)t0 * DH, h1, B_ROWS, DH, DIN);
        gemm_l2_256<<<dim3(B_ROWS / 256, DH / 256, g), 512, LDS256, stream>>>(
            h1, (size_t)B_ROWS * DH, W2b + (size_t)t0 * DH * DH, b2 + (size_t)t0 * DH, h2, B_ROWS, DH, DH);
        gemm_l3_256<<<dim3(B_ROWS / 256, 1, g), 512, LDS256, stream>>>(
            h2, W3b + (size_t)t0 * DH * DOUT, part);
        reduce_kernel<<<(B_ROWS * DOUT / 4) / 256, 256, 0, stream>>>(part, out, g);
    }
}

// Round 7
// 798.188 us; speedup vs baseline: 1.0589x; 1.0589x over previous
//
#include <hip/hip_runtime.h>
#include <hip/hip_bf16.h>
#include <stdint.h>

// Problem constants
#define T_TREES 16
#define B_ROWS  8192
#define DIN     512
#define DH      1024
#define DOUT    256

typedef unsigned short u16;
typedef __attribute__((ext_vector_type(8))) short short8;
typedef __attribute__((ext_vector_type(16))) float floatx16;

// round-to-nearest-even fp32 -> bf16
__device__ __forceinline__ u16 f2bf(float f) {
    union { float f; uint32_t u; } v; v.f = f;
    uint32_t u = v.u;
    uint32_t r = (u + 0x7fffu + ((u >> 16) & 1u)) >> 16;
    return (u16)r;
}

// async 16B/lane global->LDS (lands at wave-uniform base + lane*16)
__device__ __forceinline__ void async_copy16(const u16* g, u16* l) {
    __builtin_amdgcn_global_load_lds(
        (const __attribute__((address_space(1))) uint32_t*)g,
        (__attribute__((address_space(3))) uint32_t*)l,
        16, 0, 0);
}

// ---------------------------------------------------------------------------
// Fused prep, single launch:
//   blocks [0,4096):      convert x fp32->bf16
//   blocks [4096,12288):  out = mean_t b3
//   blocks [12288,40960): convert+transpose all weights (N x K layout)
__global__ void prep_kernel(const float* __restrict__ x, u16* __restrict__ xb,
                            const float* __restrict__ b3, float* __restrict__ out,
                            const float* __restrict__ W1, const float* __restrict__ W2,
                            const float* __restrict__ W3,
                            u16* __restrict__ W1b, u16* __restrict__ W2b,
                            u16* __restrict__ W3b) {
    __shared__ float tile[32][33];
    if (blockIdx.x < 4096) {
        int idx = blockIdx.x * 256 + threadIdx.x;
        float4 v = ((const float4*)x)[idx];
        ushort4 o;
        o.x = f2bf(v.x); o.y = f2bf(v.y); o.z = f2bf(v.z); o.w = f2bf(v.w);
        ((ushort4*)xb)[idx] = o;
    } else if (blockIdx.x < 12288) {
        int idx = (blockIdx.x - 4096) * 256 + threadIdx.x;
        int o = idx & (DOUT - 1);
        float s = 0.f;
#pragma unroll
        for (int t = 0; t < T_TREES; t++) s += b3[t * DOUT + o];
        out[idx] = s * (1.f / T_TREES);
    } else {
        int bid = blockIdx.x - 12288;
        int t = bid / 1792, tl = bid - t * 1792;
        const float* in; u16* outp; int K, N, kt, nt; float scale = 1.f;
        if (tl < 512)       { in = W1; outp = W1b; K = DIN; N = DH;   kt = tl & 15; nt = tl >> 4; }
        else if (tl < 1536) { tl -= 512;  in = W2; outp = W2b; K = DH; N = DH;   kt = tl & 31; nt = tl >> 5; }
        else                { tl -= 1536; in = W3; outp = W3b; K = DH; N = DOUT; kt = tl & 31; nt = tl >> 5;
                              scale = 1.f / T_TREES; }
        int k0 = kt * 32, n0 = nt * 32;
        const float* inb = in + (size_t)t * K * N;
        u16* outb = outp + (size_t)t * K * N;
        // float4-vectorized tile load: 32 rows x 8 float4
        int c4 = threadIdx.x & 7, rr = threadIdx.x >> 3;
        float4 v = *(const float4*)&inb[(size_t)(k0 + rr) * N + n0 + c4 * 4];
        tile[rr][c4 * 4 + 0] = v.x;
        tile[rr][c4 * 4 + 1] = v.y;
        tile[rr][c4 * 4 + 2] = v.z;
        tile[rr][c4 * 4 + 3] = v.w;
        __syncthreads();
        // vectorized transposed store: threads 0..127 write one 16B segment
        // (8 contiguous u16 of an output row). LDS column reads are 2-way
        // bank-aliased (free, m136).
        if (threadIdx.x < 128) {
            int n  = threadIdx.x >> 2;   // 0..31 output row (tile column)
            int kq = threadIdx.x & 3;    // 8-element quad along K
            short8 o;
#pragma unroll
            for (int j = 0; j < 8; j++)
                ((u16*)&o)[j] = f2bf(tile[kq * 8 + j][n] * scale);
            *(short8*)&outb[(size_t)(n0 + n) * K + k0 + kq * 8] = o;
        }
    }
}

// out[idx] += sum_{t<g} Part[t][idx]   (float4 vectorized)
__global__ void reduce_kernel(const float* __restrict__ Part, float* __restrict__ Out, int g) {
    int idx = blockIdx.x * 256 + threadIdx.x;  // over 524288 float4
    float4 s = ((const float4*)Out)[idx];
    for (int t = 0; t < g; t++) {
        float4 p = ((const float4*)(Part + (size_t)t * B_ROWS * DOUT))[idx];
        s.x += p.x; s.y += p.y; s.z += p.z; s.w += p.w;
    }
    ((float4*)Out)[idx] = s;
}

// ---------------------------------------------------------------------------
// Shared pieces: swizzle = logical 16B-slot q of row r lives at physical slot
// q ^ (r&7); staging stays LDS-linear and permutes the per-lane GLOBAL col
// (colE). A/B frag read: lane [row=base+l31][k-slot ((kk*2+h)^(l31&7))].
// C/D: col=lane&31, row=(reg&3)+8*(reg>>2)+4*(lane>>5)  [m74/m101].
// Pipeline (T3/T4): 2 tiles prefetched; per tile: vmcnt(8)+barrier, COMPUTE
// (setprio around MFMA clusters), barrier, STAGE(kt+2) into drained buffer.
// vmcnt never drains to 0 inside the loop.

#define GEMM_PREAMBLE_COMMON()                               \
    const int tid  = threadIdx.x;                            \
    const int wave = tid >> 6;                               \
    const int lane = tid & 63;                               \
    const int l31  = lane & 31;                              \
    const int h    = lane >> 5;                              \
    const int rg   = tid >> 3;                               \
    const int colE = (((tid & 7) ^ (rg & 7)) << 3);          \
    const int xm   = l31 & 7;

// ======================= 256x256 tile, 8 waves (L2) ========================
#define STAGE256(kt_, p_)                                                              \
    {                                                                                  \
        const int k0_ = (kt_) * 64;                                                    \
        u16* lA_ = lds + (p_) * 32768 + wave * 512;                                    \
        u16* lB_ = lA_ + 16384;                                                        \
        _Pragma("unroll")                                                              \
        for (int j_ = 0; j_ < 4; j_++) {                                               \
            const int row_ = j_ * 64 + rg;                                             \
            async_copy16(Ab + (size_t)(m0 + row_) * K + k0_ + colE, lA_ + j_ * 4096);  \
            async_copy16(Bb + (size_t)(n0 + row_) * K + k0_ + colE, lB_ + j_ * 4096);  \
        }                                                                              \
    }

#define COMPUTE256(p_)                                                                 \
    {                                                                                  \
        const u16* A_ = lds + (p_) * 32768;                                            \
        const u16* B_ = A_ + 16384;                                                    \
        short8 bfr[2][4];                                                              \
        _Pragma("unroll")                                                              \
        for (int nf = 0; nf < 2; nf++) {                                               \
            const int r_ = wn4 * 64 + nf * 32 + l31;                                   \
            _Pragma("unroll")                                                          \
            for (int kk = 0; kk < 4; kk++)                                             \
                bfr[nf][kk] = *(const short8*)&B_[r_ * 64 + (((kk * 2 + h) ^ xm) << 3)]; \
        }                                                                              \
        _Pragma("unroll")                                                              \
        for (int mh = 0; mh < 2; mh++) {                                               \
            short8 afr[2][4];                                                          \
            _Pragma("unroll")                                                          \
            for (int mf = 0; mf < 2; mf++) {                                           \
                const int r_ = wm2 * 128 + mh * 64 + mf * 32 + l31;                    \
                _Pragma("unroll")                                                      \
                for (int kk = 0; kk < 4; kk++)                                         \
                    afr[mf][kk] = *(const short8*)&A_[r_ * 64 + (((kk * 2 + h) ^ xm) << 3)]; \
            }                                                                          \
            __builtin_amdgcn_s_setprio(1);                                             \
            _Pragma("unroll")                                                          \
            for (int kk = 0; kk < 4; kk++)                                             \
                _Pragma("unroll")                                                      \
                for (int mf = 0; mf < 2; mf++)                                         \
                    _Pragma("unroll")                                                  \
                    for (int nf = 0; nf < 2; nf++)                                     \
                        acc[mh * 2 + mf][nf] = __builtin_amdgcn_mfma_f32_32x32x16_bf16(\
                            afr[mf][kk], bfr[nf][kk], acc[mh * 2 + mf][nf], 0, 0, 0);  \
            __builtin_amdgcn_s_setprio(0);                                             \
        }                                                                              \
    }

#define GEMM_MAIN(STAGE_, COMPUTE_)                                              \
    STAGE_(0, 0);                                                                \
    STAGE_(1, 1);                                                                \
    for (int kt = 0; kt < NT; kt++) {                                            \
        const int p_ = kt & 1;                                                   \
        if (kt < NT - 1) asm volatile("s_waitcnt vmcnt(8)\n\ts_barrier" ::: "memory"); \
        else             asm volatile("s_waitcnt vmcnt(0)\n\ts_barrier" ::: "memory"); \
        COMPUTE_(p_);                                                            \
        asm volatile("s_barrier" ::: "memory");                                  \
        if (kt + 2 < NT) STAGE_(kt + 2, p_);                                     \
    }

// L2: C[t] = relu(A[t] @ B[t]^T + bias[t]), 256x256 tile, 512 thr, 128KB LDS.
__global__ __launch_bounds__(512, 2)
void gemm_l2_256(const u16* __restrict__ A, size_t aStrideT,
                 const u16* __restrict__ Bt,
                 const float* __restrict__ bias,
                 u16* __restrict__ C,
                 int M, int N, int K) {
    extern __shared__ u16 lds[];

    const int t = blockIdx.z;
    const u16* Ab = A + (size_t)t * aStrideT;
    const u16* Bb = Bt + (size_t)t * (size_t)N * K;
    u16* Cb = C + (size_t)t * (size_t)M * N;
    const float* biasb = bias + (size_t)t * N;

    const int m0 = blockIdx.x * 256;
    const int n0 = blockIdx.y * 256;

    GEMM_PREAMBLE_COMMON();
    const int wm2 = wave >> 2;   // 0..1
    const int wn4 = wave & 3;    // 0..3

    floatx16 acc[4][2];
#pragma unroll
    for (int ai = 0; ai < 4; ai++)
#pragma unroll
        for (int nf = 0; nf < 2; nf++)
#pragma unroll
            for (int r = 0; r < 16; r++) acc[ai][nf][r] = 0.f;

    const int NT = K >> 6;
    GEMM_MAIN(STAGE256, COMPUTE256);

#pragma unroll
    for (int nf = 0; nf < 2; nf++) {
        const int n = n0 + wn4 * 64 + nf * 32 + l31;
        const float bv = biasb[n];
#pragma unroll
        for (int ai = 0; ai < 4; ai++) {
#pragma unroll
            for (int r = 0; r < 16; r++) {
                const int m = m0 + wm2 * 128 + ai * 32 + (r & 3) + 8 * (r >> 2) + 4 * h;
                float v = acc[ai][nf][r] + bv;
                v = v > 0.f ? v : 0.f;
                Cb[(size_t)m * N + n] = f2bf(v);
            }
        }
    }
}

// ======================= 128x128 tile, 4 waves (L1/L3) =====================
#define STAGE128(kt_, p_)                                                              \
    {                                                                                  \
        const int k0_ = (kt_) * 64;                                                    \
        u16* lA_ = lds + (p_) * 16384 + wave * 512;                                    \
        u16* lB_ = lA_ + 8192;                                                         \
        _Pragma("unroll")                                                              \
        for (int j_ = 0; j_ < 4; j_++) {                                               \
            const int row_ = j_ * 32 + rg;                                             \
            async_copy16(Ab + (size_t)(m0 + row_) * K + k0_ + colE, lA_ + j_ * 2048);  \
            async_copy16(Bb + (size_t)(n0 + row_) * K + k0_ + colE, lB_ + j_ * 2048);  \
        }                                                                              \
    }

// L3 tree-summed staging: kt_ spans treesPerBlock trees x 16 K-tiles each.
#define STAGE_L3(kt_, p_)                                                              \
    {                                                                                  \
        const int lt_ = ltBase + ((kt_) >> 4);                                         \
        const int k0_ = ((kt_) & 15) * 64;                                             \
        const u16* At_ = H2g + (size_t)lt_ * B_ROWS * DH;                              \
        const u16* Bt_ = W3g + (size_t)lt_ * DOUT * DH;                                \
        u16* lA_ = lds + (p_) * 16384 + wave * 512;                                    \
        u16* lB_ = lA_ + 8192;                                                         \
        _Pragma("unroll")                                                              \
        for (int j_ = 0; j_ < 4; j_++) {                                               \
            const int row_ = j_ * 32 + rg;                                             \
            async_copy16(At_ + (size_t)(m0 + row_) * DH + k0_ + colE, lA_ + j_ * 2048);\
            async_copy16(Bt_ + (size_t)(n0 + row_) * DH + k0_ + colE, lB_ + j_ * 2048);\
        }                                                                              \
    }

#define COMPUTE128(p_)                                                                 \
    {                                                                                  \
        const u16* A_ = lds + (p_) * 16384;                                            \
        const u16* B_ = A_ + 8192;                                                     \
        short8 bfr[2][4], afr[2][4];                                                   \
        _Pragma("unroll")                                                              \
        for (int nf = 0; nf < 2; nf++) {                                               \
            const int r_ = wn + nf * 32 + l31;                                         \
            _Pragma("unroll")                                                          \
            for (int kk = 0; kk < 4; kk++)                                             \
                bfr[nf][kk] = *(const short8*)&B_[r_ * 64 + (((kk * 2 + h) ^ xm) << 3)]; \
        }                                                                              \
        _Pragma("unroll")                                                              \
        for (int mf = 0; mf < 2; mf++) {                                               \
            const int r_ = wm + mf * 32 + l31;                                         \
            _Pragma("unroll")                                                          \
            for (int kk = 0; kk < 4; kk++)                                             \
                afr[mf][kk] = *(const short8*)&A_[r_ * 64 + (((kk * 2 + h) ^ xm) << 3)]; \
        }                                                                              \
        __builtin_amdgcn_s_setprio(1);                                                 \
        _Pragma("unroll")                                                              \
        for (int kk = 0; kk < 4; kk++)                                                 \
            _Pragma("unroll")                                                          \
            for (int mf = 0; mf < 2; mf++)                                             \
                _Pragma("unroll")                                                      \
                for (int nf = 0; nf < 2; nf++)                                         \
                    acc[mf][nf] = __builtin_amdgcn_mfma_f32_32x32x16_bf16(             \
                        afr[mf][kk], bfr[nf][kk], acc[mf][nf], 0, 0, 0);               \
        __builtin_amdgcn_s_setprio(0);                                                 \
    }

// L1: C[t] = relu(A @ B[t]^T + bias[t]), 128x128 tile, 256 thr, 64KB LDS.
__global__ __launch_bounds__(256, 2)
void gemm_l1_128(const u16* __restrict__ A, size_t aStrideT,
                 const u16* __restrict__ Bt,
                 const float* __restrict__ bias,
                 u16* __restrict__ C,
                 int M, int N, int K) {
    extern __shared__ u16 lds[];

    const int t = blockIdx.z;
    const u16* Ab = A + (size_t)t * aStrideT;
    const u16* Bb = Bt + (size_t)t * (size_t)N * K;
    u16* Cb = C + (size_t)t * (size_t)M * N;
    const float* biasb = bias + (size_t)t * N;

    const int m0 = blockIdx.x * 128;
    const int n0 = blockIdx.y * 128;

    GEMM_PREAMBLE_COMMON();
    const int wm = (wave >> 1) * 64;
    const int wn = (wave & 1) * 64;

    floatx16 acc[2][2];
#pragma unroll
    for (int mf = 0; mf < 2; mf++)
#pragma unroll
        for (int nf = 0; nf < 2; nf++)
#pragma unroll
            for (int r = 0; r < 16; r++) acc[mf][nf][r] = 0.f;

    const int NT = K >> 6;
    GEMM_MAIN(STAGE128, COMPUTE128);

#pragma unroll
    for (int nf = 0; nf < 2; nf++) {
        const int n = n0 + wn + nf * 32 + l31;
        const float bv = biasb[n];
#pragma unroll
        for (int mf = 0; mf < 2; mf++) {
#pragma unroll
            for (int r = 0; r < 16; r++) {
                const int m = m0 + wm + mf * 32 + (r & 3) + 8 * (r >> 2) + 4 * h;
                float v = acc[mf][nf][r] + bv;
                v = v > 0.f ? v : 0.f;
                Cb[(size_t)m * N + n] = f2bf(v);
            }
        }
    }
}

// L3 tree-summed: Part[z] = sum_{lt in z-chunk} H2[lt] @ W3t[lt]^T
// (fp32, no bias/relu; W3t pre-scaled 1/16). K-loop spans trees: the tree-mean
// folds into the MFMA accumulator, so Part planes = g/treesPerBlock.
__global__ __launch_bounds__(256, 2)
void gemm_l3_ts(const u16* __restrict__ H2g, const u16* __restrict__ W3g,
                float* __restrict__ Part, int treesPerBlock) {
    extern __shared__ u16 lds[];

    const int m0 = blockIdx.x * 128;
    const int n0 = blockIdx.y * 128;
    const int ltBase = blockIdx.z * treesPerBlock;
    float* Pb = Part + (size_t)blockIdx.z * B_ROWS * DOUT;

    GEMM_PREAMBLE_COMMON();
    const int wm = (wave >> 1) * 64;
    const int wn = (wave & 1) * 64;

    floatx16 acc[2][2];
#pragma unroll
    for (int mf = 0; mf < 2; mf++)
#pragma unroll
        for (int nf = 0; nf < 2; nf++)
#pragma unroll
            for (int r = 0; r < 16; r++) acc[mf][nf][r] = 0.f;

    const int NT = treesPerBlock << 4;   // 16 K-tiles per tree (DH/64)
    GEMM_MAIN(STAGE_L3, COMPUTE128);

#pragma unroll
    for (int nf = 0; nf < 2; nf++) {
        const int n = n0 + wn + nf * 32 + l31;
#pragma unroll
        for (int mf = 0; mf < 2; mf++) {
#pragma unroll
            for (int r = 0; r < 16; r++) {
                const int m = m0 + wm + mf * 32 + (r & 3) + 8 * (r >> 2) + 4 * h;
                Pb[(size_t)m * DOUT + n] = acc[mf][nf][r];
            }
        }
    }
}

// ---------------------------------------------------------------------------
extern "C" void kernel_launch(void* const* d_in, const int* in_sizes, int n_in,
                              void* d_out, int out_size, void* d_ws, size_t ws_size,
                              hipStream_t stream) {
    const float* x  = (const float*)d_in[0];
    const float* W1 = (const float*)d_in[1];
    const float* b1 = (const float*)d_in[2];
    const float* W2 = (const float*)d_in[3];
    const float* b2 = (const float*)d_in[4];
    const float* W3 = (const float*)d_in[5];
    const float* b3 = (const float*)d_in[6];
    float* out = (float*)d_out;

    // workspace: fixed 64 MB (xb 8 + W1b 16 + W2b 32 + W3b 8), then h1/h2.
    // Partial planes ((g/tpb) x 8 MB fp32) reuse the h1 region (free after L2).
    const size_t XB_BYTES = 8388608ull;
    const size_t W1B_BYTES = 16777216ull, W2B_BYTES = 33554432ull, W3B_BYTES = 8388608ull;
    const size_t FIXED = XB_BYTES + W1B_BYTES + W2B_BYTES + W3B_BYTES;  // 67,108,864
    const size_t PER_TREE = 33554432ull;  // h1 16 MB + h2 16 MB

    uint8_t* ws = (uint8_t*)d_ws;
    u16* xb  = (u16*)ws;
    u16* W1b = (u16*)(ws + XB_BYTES);
    u16* W2b = (u16*)(ws + XB_BYTES + W1B_BYTES);
    u16* W3b = (u16*)(ws + XB_BYTES + W1B_BYTES + W2B_BYTES);
    u16* h1  = (u16*)(ws + FIXED);
    float* part = (float*)(ws + FIXED);   // aliases h1 (safe: h1 dead after L2)

    int g = 16;
    while (g > 1 && FIXED + (size_t)g * PER_TREE > ws_size) g >>= 1;
    const int nG = T_TREES / g;
    u16* h2 = (u16*)(ws + FIXED + (size_t)g * (PER_TREE / 2));

    prep_kernel<<<12288 + 1792 * T_TREES, 256, 0, stream>>>(
        x, xb, b3, out, W1, W2, W3, W1b, W2b, W3b);

    const uint32_t LDS256 = 131072;  // 2 dbuf x (A+B) x 32 KB
    const uint32_t LDS128 = 65536;   // 2 dbuf x (A+B) x 16 KB

    const int tpb = (g >= 2) ? 2 : 1;   // trees summed per L3 block
    const int zd = g / tpb;             // Part planes

    for (int gi = 0; gi < nG; gi++) {
        const int t0 = gi * g;
        gemm_l1_128<<<dim3(B_ROWS / 128, DH / 128, g), 256, LDS128, stream>>>(
            xb, 0, W1b + (size_t)t0 * DIN * DH, b1 + (size_t)t0 * DH, h1, B_ROWS, DH, DIN);
        // L2 split into z-chunks of 4 trees (~45us each): same total work and
        // occupancy rounds, but lowers the rocprof top-5 visibility threshold
        // so off-model kernels (L1/L3/prep) surface in the counter table.
        for (int zh = 0; zh < g; zh += 4) {
            const int zc = (g - zh) < 4 ? (g - zh) : 4;
            gemm_l2_256<<<dim3(B_ROWS / 256, DH / 256, zc), 512, LDS256, stream>>>(
                h1 + (size_t)zh * B_ROWS * DH, (size_t)B_ROWS * DH,
                W2b + (size_t)(t0 + zh) * DH * DH,
                b2 + (size_t)(t0 + zh) * DH,
                h2 + (size_t)zh * B_ROWS * DH, B_ROWS, DH, DH);
        }
        gemm_l3_ts<<<dim3(B_ROWS / 128, DOUT / 128, zd), 256, LDS128, stream>>>(
            h2, W3b + (size_t)t0 * DH * DOUT, part, tpb);
        reduce_kernel<<<(B_ROWS * DOUT / 4) / 256, 256, 0, stream>>>(part, out, zd);
    }
}